// Round 9
// baseline (411.866 us; speedup 1.0000x reference)
//
#include <hip/hip_runtime.h>
#include <stdint.h>

#define B_ 8
#define L_ 4096
#define D_ 1024
#define M_ (B_*L_)        // 32768 rows
#define CHUNKS 128
#define TCH (L_/CHUNKS)   // 32

typedef float f32x4 __attribute__((ext_vector_type(4)));
typedef float f32x2 __attribute__((ext_vector_type(2)));
typedef short short8 __attribute__((ext_vector_type(8)));
typedef unsigned short ushort4v __attribute__((ext_vector_type(4)));

static __device__ __forceinline__ unsigned short f2bf(float f) {
  union { float f; unsigned u; } v; v.f = f;
  unsigned r = v.u + 0x7FFFu + ((v.u >> 16) & 1u);   // round-to-nearest-even
  return (unsigned short)(r >> 16);
}
static __device__ __forceinline__ float bf2f(unsigned short u) {
  union { unsigned u; float f; } v; v.u = ((unsigned)u) << 16; return v.f;
}

#define GLOAD16(g, l) \
  __builtin_amdgcn_global_load_lds((__attribute__((address_space(1))) const void*)(g), \
                                   (__attribute__((address_space(3))) void*)(l), 16, 0, 0)

// ---------------------------------------------------------------------------
// fp32 -> bf16 converts
// ---------------------------------------------------------------------------
__global__ __launch_bounds__(256)
void cvt_bf16(const float* __restrict__ src, unsigned short* __restrict__ dst, int n8)
{
  int gid = blockIdx.x * 256 + threadIdx.x;
  if (gid >= n8) return;
  const f32x4* s = (const f32x4*)(src + (size_t)gid * 8);
  f32x4 v0 = s[0], v1 = s[1];
  union { short8 v; unsigned short u[8]; } w;
  w.u[0] = f2bf(v0[0]); w.u[1] = f2bf(v0[1]); w.u[2] = f2bf(v0[2]); w.u[3] = f2bf(v0[3]);
  w.u[4] = f2bf(v1[0]); w.u[5] = f2bf(v1[1]); w.u[6] = f2bf(v1[2]); w.u[7] = f2bf(v1[3]);
  *(short8*)(dst + (size_t)gid * 8) = w.v;
}

__global__ __launch_bounds__(256)
void cvt_w3(const float* __restrict__ w0, const float* __restrict__ w1,
            const float* __restrict__ w2, unsigned short* __restrict__ dst)
{
  const int per = (D_ * D_) / 8 / 256;
  int m = blockIdx.x / per;
  int gid = (blockIdx.x % per) * 256 + threadIdx.x;
  const float* src = (m == 0) ? w0 : (m == 1) ? w1 : w2;
  const f32x4* s = (const f32x4*)(src + (size_t)gid * 8);
  f32x4 v0 = s[0], v1 = s[1];
  union { short8 v; unsigned short u[8]; } w;
  w.u[0] = f2bf(v0[0]); w.u[1] = f2bf(v0[1]); w.u[2] = f2bf(v0[2]); w.u[3] = f2bf(v0[3]);
  w.u[4] = f2bf(v1[0]); w.u[5] = f2bf(v1[1]); w.u[6] = f2bf(v1[2]); w.u[7] = f2bf(v1[3]);
  *(short8*)(dst + (size_t)m * D_ * D_ + (size_t)gid * 8) = w.v;
}

// ---------------------------------------------------------------------------
// 256x256 8-wave GEMM. Asymmetric LDS rings over full 160 KB:
//   A: ring-3 of 32KB K-tiles (96KB)  -> 8-phase issue->use lead (~1240cy > HBM)
//   B: ring-2 of 32KB K-tiles (64KB)  -> 4-phase lead (~620cy > L2/L3; weights
//      are L2-resident after the first readers on each XCD)
// Per tile: ONE issue point (ph0: [stgB(t+1), stgA(t+2)] — deadline order so
// the in-order vmcnt never force-drains a deep A prefetch for a B wait) and
// ONE wait (vmcnt(4) before ph3's final barrier, leaving only A(t+2) in
// flight). 4 phases/tile x 16 MFMA; 2 barriers/phase; fully unrolled.
// MODE 0: stacked gates Bw=[W_f;W_i]; writes rem=lin*sig(zf+b), t=tanh(zi+b)
// MODE 1: y = h*W_o^T + b_o fp32.
// A-locality dispatch: 32 co-resident blocks/XCD = {GBM bm} x {all bn}.
// ---------------------------------------------------------------------------
template<int MODE>
__global__ __launch_bounds__(512, 2)
void gemm256(const unsigned short* __restrict__ A,
             const unsigned short* __restrict__ Bw,
             const float* __restrict__ bias0,
             const float* __restrict__ bias1,
             unsigned short* __restrict__ ob0,   // rem (MODE 0)
             unsigned short* __restrict__ ob1,   // t   (MODE 0)
             float* __restrict__ of)             // y   (MODE 1)
{
  __shared__ unsigned short lds[81920];   // 160 KB: A slots 0..2 | B slots at +96KB
  char* ldsb = (char*)lds;

  const int tid  = threadIdx.x;
  const int lane = tid & 63;
  const int wid  = tid >> 6;
  const int wm   = wid >> 2;          // 0..1
  const int wn   = wid & 3;           // 0..3
  const int frow = lane & 15, ks = lane >> 4;
  const int xsw  = (ks ^ ((frow >> 1) & 3)) << 4;

  constexpr int NBN = (MODE == 0) ? 8 : 4;
  constexpr int GBM = 32 / NBN;
  const int xcd   = blockIdx.x & 7;
  const int slot  = blockIdx.x >> 3;
  const int local = slot & 31;
  const int wrnd  = slot >> 5;
  const int bm = (xcd * 16 + wrnd * GBM + (local & (GBM - 1))) * 256;
  const int bn = (local / GBM) * 256;

  const int r0  = tid >> 2;
  const int scl = ((tid & 3) ^ ((r0 >> 1) & 3)) << 4;   // pre-swizzled source slot
  const char* pA = (const char*)A  + (size_t)(bm + r0) * 2048 + scl;
  const char* pB = (const char*)Bw + (size_t)(bn + r0) * 2048 + scl;
  const int dst16 = tid * 16;

  f32x4 acc[8][4] = {};
  short8 aq[4], bq[4];

  // stage a full 256x64 bf16 K-tile (32KB = 4 gload16/thread), kk0 halves first
  auto stgA = [&](int T, int sl) {
    const char* s = pA + T * 128;
    char* d = ldsb + sl * 32768 + dst16;
    GLOAD16(s,                      d);
    GLOAD16(s + (size_t)128 * 2048, d + 8192);
    GLOAD16(s + 64,                      d + 16384);
    GLOAD16(s + 64 + (size_t)128 * 2048, d + 24576);
  };
  auto stgB = [&](int T, int sl) {
    const char* s = pB + T * 128;
    char* d = ldsb + 98304 + sl * 32768 + dst16;
    GLOAD16(s,                      d);
    GLOAD16(s + (size_t)128 * 2048, d + 8192);
    GLOAD16(s + 64,                      d + 16384);
    GLOAD16(s + 64 + (size_t)128 * 2048, d + 24576);
  };
  auto ldAB4 = [&](const char* LA, const char* LB, int kk) {
    const char* ab = LA + kk * 16384 + (wm * 128 + frow) * 64 + xsw;
    const char* bb = LB + kk * 16384 + (wn * 64 + frow) * 64 + xsw;
    aq[0] = *(const short8*)(ab);
    bq[0] = *(const short8*)(bb);
    bq[1] = *(const short8*)(bb + 1024);
    bq[2] = *(const short8*)(bb + 2048);
    bq[3] = *(const short8*)(bb + 3072);
    aq[1] = *(const short8*)(ab + 1024);
    aq[2] = *(const short8*)(ab + 2048);
    aq[3] = *(const short8*)(ab + 3072);
  };
  auto ldA4 = [&](const char* LA, int kk) {   // ih=1 rows (wm*128+64..127)
    const char* ab = LA + kk * 16384 + (wm * 128 + 64 + frow) * 64 + xsw;
    aq[0] = *(const short8*)(ab);
    aq[1] = *(const short8*)(ab + 1024);
    aq[2] = *(const short8*)(ab + 2048);
    aq[3] = *(const short8*)(ab + 3072);
  };
  auto mfma16 = [&](int ih) {
    __builtin_amdgcn_s_setprio(1);
    #pragma unroll
    for (int i2 = 0; i2 < 4; ++i2) {
      #pragma unroll
      for (int j = 0; j < 4; ++j)
        acc[ih * 4 + i2][j] =
          __builtin_amdgcn_mfma_f32_16x16x32_bf16(aq[i2], bq[j], acc[ih * 4 + i2][j], 0, 0, 0);
    }
    __builtin_amdgcn_s_setprio(0);
  };

#define BAR __builtin_amdgcn_s_barrier()
// Tile T: read A slot SA, B slot SB; optionally stage B(T+1)->SBst, A(T+2)->SAst
// (B first = deadline order). One vmcnt at end of ph3.
#define DO_TILE(T, SA, SB, SAst, SBst, STGB, STGA, WAITN)                     \
  {                                                                           \
    const char* LA = ldsb + (SA) * 32768;                                     \
    const char* LB = ldsb + 98304 + (SB) * 32768;                             \
    ldAB4(LA, LB, 0);                                                         \
    if (STGB) stgB((T) + 1, (SBst));                                          \
    if (STGA) stgA((T) + 2, (SAst));                                          \
    BAR; mfma16(0); BAR;                                                      \
    ldA4(LA, 0);                                                              \
    BAR; mfma16(1); BAR;                                                      \
    ldAB4(LA, LB, 1);                                                         \
    BAR; mfma16(0); BAR;                                                      \
    ldA4(LA, 1);                                                              \
    BAR; mfma16(1);                                                           \
    if ((WAITN) >= 0) {                                                       \
      if ((WAITN) == 4) asm volatile("s_waitcnt vmcnt(4)" ::: "memory");      \
      else              asm volatile("s_waitcnt vmcnt(0)" ::: "memory");      \
    }                                                                         \
    BAR;                                                                      \
  }

  // prologue (deadline order): B0,A0,B1,A1 -> wait B0,A0 done (8 newest left)
  stgB(0, 0); stgA(0, 0);
  stgB(1, 1); stgA(1, 1);
  asm volatile("s_waitcnt vmcnt(8)" ::: "memory");
  BAR;

  // slots: SA=T%3, SAst=(T+2)%3, SB=T%2, SBst=(T+1)%2
  DO_TILE( 0, 0, 0, 2, 1, false, true,  4);   // B1 pre-issued
  DO_TILE( 1, 1, 1, 0, 0, true,  true,  4);
  DO_TILE( 2, 2, 0, 1, 1, true,  true,  4);
  DO_TILE( 3, 0, 1, 2, 0, true,  true,  4);
  DO_TILE( 4, 1, 0, 0, 1, true,  true,  4);
  DO_TILE( 5, 2, 1, 1, 0, true,  true,  4);
  DO_TILE( 6, 0, 0, 2, 1, true,  true,  4);
  DO_TILE( 7, 1, 1, 0, 0, true,  true,  4);
  DO_TILE( 8, 2, 0, 1, 1, true,  true,  4);
  DO_TILE( 9, 0, 1, 2, 0, true,  true,  4);
  DO_TILE(10, 1, 0, 0, 1, true,  true,  4);
  DO_TILE(11, 2, 1, 1, 0, true,  true,  4);
  DO_TILE(12, 0, 0, 2, 1, true,  true,  4);
  DO_TILE(13, 1, 1, 0, 0, true,  true,  4);
  DO_TILE(14, 2, 0, 1, 1, true,  false, 0);   // B15 only; drain all
  DO_TILE(15, 0, 1, 0, 0, false, false, -1);
#undef DO_TILE
#undef BAR

  // epilogue: C/D mapping col=lane&15, row=(lane>>4)*4+r
  if constexpr (MODE == 0) {
    const int plane = bn >> 10;                 // 0: rem, 1: tanh
    const int cb    = bn & 1023;
    unsigned short* ob = plane ? ob1 : ob0;
    const float* bs    = plane ? bias1 : bias0;
    float bv[4];
    #pragma unroll
    for (int j = 0; j < 4; ++j) bv[j] = bs[cb + wn * 64 + j * 16 + frow];
    #pragma unroll
    for (int ii = 0; ii < 8; ++ii) {
      int row = bm + wm * 128 + ii * 16 + ks * 4;
      #pragma unroll
      for (int j = 0; j < 4; ++j) {
        int col = cb + wn * 64 + j * 16 + frow;
        float lin = (float)col * (1.0f / 1023.0f);
        #pragma unroll
        for (int r = 0; r < 4; ++r) {
          float z = acc[ii][j][r] + bv[j];
          float v;
          if (plane == 0) {
            v = lin / (1.0f + __expf(-z));             // rem (small, bf16-safe)
          } else {
            float e2 = __expf(2.0f * z);
            v = 1.0f - 2.0f / (e2 + 1.0f);             // tanh
          }
          ob[(size_t)(row + r) * D_ + col] = f2bf(v);
        }
      }
    }
  } else {
    float bv[4];
    #pragma unroll
    for (int j = 0; j < 4; ++j) bv[j] = bias0[bn + wn * 64 + j * 16 + frow];
    #pragma unroll
    for (int ii = 0; ii < 8; ++ii) {
      int row = bm + wm * 128 + ii * 16 + ks * 4;
      #pragma unroll
      for (int j = 0; j < 4; ++j) {
        int col = bn + wn * 64 + j * 16 + frow;
        #pragma unroll
        for (int r = 0; r < 4; ++r)
          of[(size_t)(row + r) * D_ + col] = acc[ii][j][r] + bv[j];
      }
    }
  }
}

// ---------------------------------------------------------------------------
// Chunked parallel scan over precomputed (rem, t), 4 channels/thread.
// f = 1 - rem (fp32);  h_t = f*h_{t-1} + t*rem
// ---------------------------------------------------------------------------
__global__ __launch_bounds__(256)
void scan_partial_b(const unsigned short* __restrict__ rb,
                    const unsigned short* __restrict__ tb,
                    float* __restrict__ Ag, float* __restrict__ Ug)
{
  int blk = blockIdx.x;
  int b = blk >> 7, c = blk & (CHUNKS - 1);
  int e = threadIdx.x << 2;
  size_t base = ((size_t)b * L_ + (size_t)c * TCH) * D_ + e;
  f32x4 a = {1.f,1.f,1.f,1.f}, u = {0.f,0.f,0.f,0.f};
  for (int t = 0; t < TCH; ++t) {
    ushort4v r4 = *(const ushort4v*)(rb + base + (size_t)t * D_);
    ushort4v t4 = *(const ushort4v*)(tb + base + (size_t)t * D_);
    #pragma unroll
    for (int j = 0; j < 4; ++j) {
      float rem = bf2f(r4[j]);
      float f   = 1.0f - rem;
      float inp = bf2f(t4[j]) * rem;
      u[j] = fmaf(f, u[j], inp);
      a[j] *= f;
    }
  }
  size_t o = (size_t)(b * CHUNKS + c) * D_ + e;
  *(f32x4*)(Ag + o) = a;
  *(f32x4*)(Ug + o) = u;
}

__global__ __launch_bounds__(256)
void scan_carry(const float* __restrict__ Ag, const float* __restrict__ Ug,
                const float* __restrict__ hidden, float* __restrict__ Hin)
{
  int gid = blockIdx.x * 256 + threadIdx.x;  // B_*D_/4 threads
  int b = gid >> 8;
  int e = (gid & 255) << 2;
  f32x4 h = *(const f32x4*)(hidden + (size_t)b * D_ + e);
  for (int c = 0; c < CHUNKS; ++c) {
    size_t o = (size_t)(b * CHUNKS + c) * D_ + e;
    *(f32x4*)(Hin + o) = h;
    f32x4 A = *(const f32x4*)(Ag + o);
    f32x4 U = *(const f32x4*)(Ug + o);
    h = A * h + U;
  }
}

__global__ __launch_bounds__(256)
void scan_apply_b(const unsigned short* __restrict__ rb,
                  const unsigned short* __restrict__ tb,
                  const float* __restrict__ Hin,
                  float* __restrict__ hout, unsigned short* __restrict__ hb)
{
  int blk = blockIdx.x;
  int b = blk >> 7, c = blk & (CHUNKS - 1);
  int e = threadIdx.x << 2;
  size_t base = ((size_t)b * L_ + (size_t)c * TCH) * D_ + e;
  f32x4 h = *(const f32x4*)(Hin + (size_t)(b * CHUNKS + c) * D_ + e);
  for (int t = 0; t < TCH; ++t) {
    size_t o = base + (size_t)t * D_;
    ushort4v r4 = *(const ushort4v*)(rb + o);
    ushort4v t4 = *(const ushort4v*)(tb + o);
    #pragma unroll
    for (int j = 0; j < 4; ++j) {
      float rem = bf2f(r4[j]);
      float f   = 1.0f - rem;
      float inp = bf2f(t4[j]) * rem;
      h[j] = fmaf(f, h[j], inp);
    }
    *(f32x4*)(hout + o) = h;
    ushort4v p;
    p[0] = f2bf(h[0]); p[1] = f2bf(h[1]); p[2] = f2bf(h[2]); p[3] = f2bf(h[3]);
    *(ushort4v*)(hb + o) = p;
  }
}

// ---------------------------------------------------------------------------
// Slow fallback (fp32 in) — only if ws too small (never expected).
// ---------------------------------------------------------------------------
template<int MODE>
__global__ __launch_bounds__(256, 2)
void gemm_slow(const float* __restrict__ A, const float* __restrict__ B0,
               const float* __restrict__ B1, const float* __restrict__ bias0,
               const float* __restrict__ bias1, float* __restrict__ out0,
               float* __restrict__ out1)
{
  constexpr int BK = 32;
  __shared__ unsigned short As[128 * BK];
  __shared__ unsigned short Bs0[128 * BK];
  __shared__ unsigned short Bs1[(MODE == 0) ? (128 * BK) : 8];

  const int tid = threadIdx.x, lane = tid & 63, wave = tid >> 6;
  const int wr = wave >> 1, wc = wave & 1;
  const int bm = blockIdx.x * 128, bn = blockIdx.y * 128;
  f32x4 acc0[4][4] = {};
  f32x4 acc1[(MODE == 0) ? 4 : 1][(MODE == 0) ? 4 : 1] = {};
  const int frow = lane & 15, kslot = lane >> 4;
  const int xs = kslot ^ (frow & 3);

  auto stage = [&](const float* src, unsigned short* dst) {
    #pragma unroll
    for (int p = 0; p < 4; ++p) {
      int g = p * 256 + tid;
      int row = g >> 3, kq = (g & 7) << 2;
      f32x4 v = *(const f32x4*)(src + (size_t)row * D_ + kq);
      ushort4v w;
      w[0] = f2bf(v[0]); w[1] = f2bf(v[1]); w[2] = f2bf(v[2]); w[3] = f2bf(v[3]);
      int byte = kq << 1, slot = byte >> 4, sub = byte & 15;
      int off = row * 64 + ((slot ^ (row & 3)) << 4) + sub;
      *(ushort4v*)((char*)dst + off) = w;
    }
  };

  for (int k0 = 0; k0 < D_; k0 += BK) {
    stage(A + (size_t)bm * D_ + k0, As);
    stage(B0 + (size_t)bn * D_ + k0, Bs0);
    if constexpr (MODE == 0) stage(B1 + (size_t)bn * D_ + k0, Bs1);
    __syncthreads();
    short8 af[4], bf0[4], bf1[4];
    #pragma unroll
    for (int i = 0; i < 4; ++i) {
      int ar = wr * 64 + i * 16 + frow;
      af[i] = *(const short8*)((const char*)As + ar * 64 + (xs << 4));
      int br = wc * 64 + i * 16 + frow;
      bf0[i] = *(const short8*)((const char*)Bs0 + br * 64 + (xs << 4));
      if constexpr (MODE == 0)
        bf1[i] = *(const short8*)((const char*)Bs1 + br * 64 + (xs << 4));
    }
    #pragma unroll
    for (int i = 0; i < 4; ++i)
      #pragma unroll
      for (int j = 0; j < 4; ++j) {
        acc0[i][j] = __builtin_amdgcn_mfma_f32_16x16x32_bf16(af[i], bf0[j], acc0[i][j], 0, 0, 0);
        if constexpr (MODE == 0)
          acc1[i][j] = __builtin_amdgcn_mfma_f32_16x16x32_bf16(af[i], bf1[j], acc1[i][j], 0, 0, 0);
      }
    __syncthreads();
  }
  #pragma unroll
  for (int i = 0; i < 4; ++i)
    #pragma unroll
    for (int j = 0; j < 4; ++j)
      #pragma unroll
      for (int r = 0; r < 4; ++r) {
        int row = bm + wr * 64 + i * 16 + (lane >> 4) * 4 + r;
        int col = bn + wc * 64 + j * 16 + (lane & 15);
        size_t idx = (size_t)row * D_ + col;
        if constexpr (MODE == 0) {
          float zf = acc0[i][j][r] + bias0[col];
          float linv = (float)col * (1.0f / 1023.0f);
          float rem = linv / (1.0f + __expf(-zf));
          float zi = acc1[i][j][r] + bias1[col];
          float e2 = __expf(2.0f * zi);
          float th = 1.0f - 2.0f / (e2 + 1.0f);
          out0[idx] = 1.0f - rem;
          out1[idx] = th * rem;
        } else {
          out0[idx] = acc0[i][j][r] + bias0[col];
        }
      }
}

__global__ __launch_bounds__(256)
void scan_partial_f(const float* __restrict__ p0, const float* __restrict__ p1,
                    float* __restrict__ Ag, float* __restrict__ Ug)
{
  int blk = blockIdx.x;
  int b = blk / (CHUNKS * 2);
  int c = (blk >> 1) & (CHUNKS - 1);
  int e = ((blk & 1) << 9) + threadIdx.x * 2;
  size_t base = ((size_t)b * L_ + (size_t)c * TCH) * D_ + e;
  f32x2 a = {1.0f, 1.0f}, u = {0.0f, 0.0f};
  for (int t = 0; t < TCH; ++t) {
    f32x2 f = *(const f32x2*)(p0 + base + (size_t)t * D_);
    f32x2 i = *(const f32x2*)(p1 + base + (size_t)t * D_);
    u = f * u + i;
    a = a * f;
  }
  size_t o = (size_t)(b * CHUNKS + c) * D_ + e;
  *(f32x2*)(Ag + o) = a;
  *(f32x2*)(Ug + o) = u;
}

__global__ __launch_bounds__(256)
void scan_apply_f(const float* __restrict__ p0, float* __restrict__ p1_io,
                  const float* __restrict__ Hin)
{
  int blk = blockIdx.x;
  int b = blk / (CHUNKS * 2);
  int c = (blk >> 1) & (CHUNKS - 1);
  int e = ((blk & 1) << 9) + threadIdx.x * 2;
  size_t base = ((size_t)b * L_ + (size_t)c * TCH) * D_ + e;
  f32x2 h = *(const f32x2*)(Hin + (size_t)(b * CHUNKS + c) * D_ + e);
  for (int t = 0; t < TCH; ++t) {
    size_t o = base + (size_t)t * D_;
    f32x2 f = *(const f32x2*)(p0 + o);
    f32x2 i = *(const f32x2*)(p1_io + o);
    h = f * h + i;
    *(f32x2*)(p1_io + o) = h;
  }
}

// ---------------------------------------------------------------------------
extern "C" void kernel_launch(void* const* d_in, const int* in_sizes, int n_in,
                              void* d_out, int out_size, void* d_ws, size_t ws_size,
                              hipStream_t stream)
{
  const float* x      = (const float*)d_in[0];
  const float* hidden = (const float*)d_in[1];
  const float* W_f    = (const float*)d_in[2];
  const float* b_f    = (const float*)d_in[3];
  const float* W_i    = (const float*)d_in[4];
  const float* b_i    = (const float*)d_in[5];
  const float* W_o    = (const float*)d_in[6];
  const float* b_o    = (const float*)d_in[7];

  float* y = (float*)d_out;
  float* h = y + (size_t)M_ * D_;

  const size_t xb_elems = (size_t)M_ * D_;
  const size_t w_elems  = (size_t)D_ * D_;
  const size_t agg      = (size_t)B_ * CHUNKS * D_;
  const size_t need = (xb_elems * 3 + 3 * w_elems) * 2 + agg * 3 * 4;

  if (ws_size >= need) {
    unsigned short* xb  = (unsigned short*)d_ws;       // bf16 x, later bf16 h
    unsigned short* wfb = xb + xb_elems;               // [W_f;W_i] stacked
    unsigned short* wib = wfb + w_elems;
    unsigned short* wob = wib + w_elems;
    unsigned short* rbv = wob + w_elems;               // bf16 rem
    unsigned short* tbv = rbv + xb_elems;              // bf16 tanh
    float* Ag  = (float*)(tbv + xb_elems);
    float* Ug  = Ag + agg;
    float* Hin = Ug + agg;

    cvt_bf16<<<(int)(xb_elems / 8 / 256), 256, 0, stream>>>(x, xb, (int)(xb_elems / 8));
    cvt_w3<<<3 * (int)(w_elems / 8 / 256), 256, 0, stream>>>(W_f, W_i, W_o, wfb);

    gemm256<0><<<1024, 512, 0, stream>>>(xb, wfb, b_f, b_i, rbv, tbv, nullptr);

    int pblocks = B_ * CHUNKS;               // 1024
    scan_partial_b<<<pblocks, 256, 0, stream>>>(rbv, tbv, Ag, Ug);
    scan_carry<<<(B_ * D_ / 4) / 256, 256, 0, stream>>>(Ag, Ug, hidden, Hin);
    scan_apply_b<<<pblocks, 256, 0, stream>>>(rbv, tbv, Hin, h, xb);

    gemm256<1><<<512, 512, 0, stream>>>(xb, wob, b_o, nullptr, nullptr, nullptr, y);
  } else {
    float* Ag  = (float*)d_ws;
    float* Ug  = Ag + agg;
    float* Hin = Ug + agg;
    dim3 gg(M_ / 128, D_ / 128);
    int pblocks = B_ * CHUNKS * 2;

    gemm_slow<0><<<gg, 256, 0, stream>>>(x, W_f, W_i, b_f, b_i, y, h);
    scan_partial_f<<<pblocks, 256, 0, stream>>>(y, h, Ag, Ug);
    scan_carry<<<(B_ * D_ / 4) / 256, 256, 0, stream>>>(Ag, Ug, hidden, Hin);
    scan_apply_f<<<pblocks, 256, 0, stream>>>(y, h, Hin);
    gemm_slow<1><<<gg, 256, 0, stream>>>(h, W_o, nullptr, b_o, nullptr, y, nullptr);
  }
}

// Round 10
// 386.553 us; speedup vs baseline: 1.0655x; 1.0655x over previous
//
#include <hip/hip_runtime.h>
#include <stdint.h>

#define B_ 8
#define L_ 4096
#define D_ 1024
#define M_ (B_*L_)        // 32768 rows
#define CHUNKS 128
#define TCH (L_/CHUNKS)   // 32

typedef float f32x4 __attribute__((ext_vector_type(4)));
typedef float f32x2 __attribute__((ext_vector_type(2)));
typedef short short8 __attribute__((ext_vector_type(8)));
typedef unsigned short ushort4v __attribute__((ext_vector_type(4)));

static __device__ __forceinline__ unsigned short f2bf(float f) {
  union { float f; unsigned u; } v; v.f = f;
  unsigned r = v.u + 0x7FFFu + ((v.u >> 16) & 1u);   // round-to-nearest-even
  return (unsigned short)(r >> 16);
}
static __device__ __forceinline__ float bf2f(unsigned short u) {
  union { unsigned u; float f; } v; v.u = ((unsigned)u) << 16; return v.f;
}

#define GLOAD16(g, l) \
  __builtin_amdgcn_global_load_lds((__attribute__((address_space(1))) const void*)(g), \
                                   (__attribute__((address_space(3))) void*)(l), 16, 0, 0)

// ---------------------------------------------------------------------------
// fp32 -> bf16 converts
// ---------------------------------------------------------------------------
__global__ __launch_bounds__(256)
void cvt_bf16(const float* __restrict__ src, unsigned short* __restrict__ dst, int n8)
{
  int gid = blockIdx.x * 256 + threadIdx.x;
  if (gid >= n8) return;
  const f32x4* s = (const f32x4*)(src + (size_t)gid * 8);
  f32x4 v0 = s[0], v1 = s[1];
  union { short8 v; unsigned short u[8]; } w;
  w.u[0] = f2bf(v0[0]); w.u[1] = f2bf(v0[1]); w.u[2] = f2bf(v0[2]); w.u[3] = f2bf(v0[3]);
  w.u[4] = f2bf(v1[0]); w.u[5] = f2bf(v1[1]); w.u[6] = f2bf(v1[2]); w.u[7] = f2bf(v1[3]);
  *(short8*)(dst + (size_t)gid * 8) = w.v;
}

__global__ __launch_bounds__(256)
void cvt_w3(const float* __restrict__ w0, const float* __restrict__ w1,
            const float* __restrict__ w2, unsigned short* __restrict__ dst)
{
  const int per = (D_ * D_) / 8 / 256;
  int m = blockIdx.x / per;
  int gid = (blockIdx.x % per) * 256 + threadIdx.x;
  const float* src = (m == 0) ? w0 : (m == 1) ? w1 : w2;
  const f32x4* s = (const f32x4*)(src + (size_t)gid * 8);
  f32x4 v0 = s[0], v1 = s[1];
  union { short8 v; unsigned short u[8]; } w;
  w.u[0] = f2bf(v0[0]); w.u[1] = f2bf(v0[1]); w.u[2] = f2bf(v0[2]); w.u[3] = f2bf(v0[3]);
  w.u[4] = f2bf(v1[0]); w.u[5] = f2bf(v1[1]); w.u[6] = f2bf(v1[2]); w.u[7] = f2bf(v1[3]);
  *(short8*)(dst + (size_t)m * D_ * D_ + (size_t)gid * 8) = w.v;
}

// ---------------------------------------------------------------------------
// 256x256 8-wave GEMM. Symmetric ring-5 chunk pipeline over full 160 KB:
//   chunk = 32 K-cols (256 rows x 32 bf16 = 16 KB); A ring-5 (80KB) +
//   B ring-5 (80KB, at +81920). Chunk c staged during chunk c-4 ->
//   issue->use lead = 4 chunks (~1240 cy > HBM ~900) for BOTH matrices.
// Per chunk: {ldB4+ldA(ih0); stgA(c+4); 16 MFMA; ldA(ih1); stgB(c+4);
//   16 MFMA; vmcnt(12) [drains exactly chunk c+1]; barrier}.
// WAR: slot(c) overwritten by chunk c+5, issued during chunk c+1 — one full
// barrier after c's last read. One barrier + one non-draining wait per chunk.
// MODE 0: stacked gates Bw=[W_f;W_i]; writes rem=lin*sig(zf+b), t=tanh(zi+b)
// MODE 1: y = h*W_o^T + b_o fp32.
// A-locality dispatch: 32 co-resident blocks/XCD = {GBM bm} x {all bn}.
// ---------------------------------------------------------------------------
template<int MODE>
__global__ __launch_bounds__(512, 2)
void gemm256(const unsigned short* __restrict__ A,
             const unsigned short* __restrict__ Bw,
             const float* __restrict__ bias0,
             const float* __restrict__ bias1,
             unsigned short* __restrict__ ob0,   // rem (MODE 0)
             unsigned short* __restrict__ ob1,   // t   (MODE 0)
             float* __restrict__ of)             // y   (MODE 1)
{
  __shared__ unsigned short lds[81920];   // 160 KB: A slots 0..4 | B slots at +81920
  char* ldsb = (char*)lds;

  const int tid  = threadIdx.x;
  const int lane = tid & 63;
  const int wid  = tid >> 6;
  const int wm   = wid >> 2;          // 0..1
  const int wn   = wid & 3;           // 0..3
  const int frow = lane & 15, ks = lane >> 4;
  const int xsw  = (ks ^ ((frow >> 1) & 3)) << 4;

  constexpr int NBN = (MODE == 0) ? 8 : 4;
  constexpr int GBM = 32 / NBN;
  const int xcd   = blockIdx.x & 7;
  const int slot  = blockIdx.x >> 3;
  const int local = slot & 31;
  const int wrnd  = slot >> 5;
  const int bm = (xcd * 16 + wrnd * GBM + (local & (GBM - 1))) * 256;
  const int bn = (local / GBM) * 256;

  const int r0  = tid >> 2;
  const int scl = ((tid & 3) ^ ((r0 >> 1) & 3)) << 4;   // pre-swizzled source slot
  const char* pA = (const char*)A  + (size_t)(bm + r0) * 2048 + scl;
  const char* pB = (const char*)Bw + (size_t)(bn + r0) * 2048 + scl;
  const int dst16 = tid * 16;

  f32x4 acc[8][4] = {};
  short8 aq[4], bq[4];

  // stage one 16KB chunk (32 K-cols) = 2 gload16/thread
  auto stgA = [&](int c, int sl) {
    const char* s = pA + c * 64;
    char* d = ldsb + sl * 16384 + dst16;
    GLOAD16(s,                      d);
    GLOAD16(s + (size_t)128 * 2048, d + 8192);
  };
  auto stgB = [&](int c, int sl) {
    const char* s = pB + c * 64;
    char* d = ldsb + 81920 + sl * 16384 + dst16;
    GLOAD16(s,                      d);
    GLOAD16(s + (size_t)128 * 2048, d + 8192);
  };
  auto ldAB4 = [&](const char* LA, const char* LB) {   // B frags + A ih0 rows
    const char* ab = LA + (wm * 128 + frow) * 64 + xsw;
    const char* bb = LB + (wn * 64 + frow) * 64 + xsw;
    aq[0] = *(const short8*)(ab);
    bq[0] = *(const short8*)(bb);
    bq[1] = *(const short8*)(bb + 1024);
    bq[2] = *(const short8*)(bb + 2048);
    bq[3] = *(const short8*)(bb + 3072);
    aq[1] = *(const short8*)(ab + 1024);
    aq[2] = *(const short8*)(ab + 2048);
    aq[3] = *(const short8*)(ab + 3072);
  };
  auto ldA4 = [&](const char* LA) {                    // A ih1 rows (+64)
    const char* ab = LA + (wm * 128 + 64 + frow) * 64 + xsw;
    aq[0] = *(const short8*)(ab);
    aq[1] = *(const short8*)(ab + 1024);
    aq[2] = *(const short8*)(ab + 2048);
    aq[3] = *(const short8*)(ab + 3072);
  };
  auto mfma16 = [&](int ih) {
    __builtin_amdgcn_s_setprio(1);
    #pragma unroll
    for (int i2 = 0; i2 < 4; ++i2) {
      #pragma unroll
      for (int j = 0; j < 4; ++j)
        acc[ih * 4 + i2][j] =
          __builtin_amdgcn_mfma_f32_16x16x32_bf16(aq[i2], bq[j], acc[ih * 4 + i2][j], 0, 0, 0);
    }
    __builtin_amdgcn_s_setprio(0);
  };

#define BAR __builtin_amdgcn_s_barrier()
#define WAITV(N) asm volatile("s_waitcnt vmcnt(" #N ")" ::: "memory")
// chunk c: read slot SL; stage chunk c+4 -> slot SG; wait WN drains chunk c+1
#define DO_CH(c, SL, SG, STG, WN)                                             \
  {                                                                           \
    const char* LA = ldsb + (SL) * 16384;                                     \
    const char* LB = ldsb + 81920 + (SL) * 16384;                             \
    ldAB4(LA, LB);                                                            \
    if (STG) stgA((c) + 4, (SG));                                             \
    mfma16(0);                                                                \
    ldA4(LA);                                                                 \
    if (STG) stgB((c) + 4, (SG));                                             \
    mfma16(1);                                                                \
    WAITV(WN);                                                                \
    BAR;                                                                      \
  }
#define DO_CH_LAST(SL)                                                        \
  {                                                                           \
    const char* LA = ldsb + (SL) * 16384;                                     \
    const char* LB = ldsb + 81920 + (SL) * 16384;                             \
    ldAB4(LA, LB);                                                            \
    mfma16(0);                                                                \
    ldA4(LA);                                                                 \
    mfma16(1);                                                                \
  }

  // prologue: chunks 0..3 (A,B interleaved; oldest = chunk 0) -> 16 loads
  stgA(0, 0); stgB(0, 0);
  stgA(1, 1); stgB(1, 1);
  stgA(2, 2); stgB(2, 2);
  stgA(3, 3); stgB(3, 3);
  WAITV(12);                          // chunk 0 resident
  BAR;

  DO_CH( 0, 0, 4, true, 12);
  DO_CH( 1, 1, 0, true, 12);
  DO_CH( 2, 2, 1, true, 12);
  DO_CH( 3, 3, 2, true, 12);
  DO_CH( 4, 4, 3, true, 12);
  DO_CH( 5, 0, 4, true, 12);
  DO_CH( 6, 1, 0, true, 12);
  DO_CH( 7, 2, 1, true, 12);
  DO_CH( 8, 3, 2, true, 12);
  DO_CH( 9, 4, 3, true, 12);
  DO_CH(10, 0, 4, true, 12);
  DO_CH(11, 1, 0, true, 12);
  DO_CH(12, 2, 1, true, 12);
  DO_CH(13, 3, 2, true, 12);
  DO_CH(14, 4, 3, true, 12);
  DO_CH(15, 0, 4, true, 12);
  DO_CH(16, 1, 0, true, 12);
  DO_CH(17, 2, 1, true, 12);
  DO_CH(18, 3, 2, true, 12);
  DO_CH(19, 4, 3, true, 12);
  DO_CH(20, 0, 4, true, 12);
  DO_CH(21, 1, 0, true, 12);
  DO_CH(22, 2, 1, true, 12);
  DO_CH(23, 3, 2, true, 12);
  DO_CH(24, 4, 3, true, 12);
  DO_CH(25, 0, 4, true, 12);
  DO_CH(26, 1, 0, true, 12);
  DO_CH(27, 2, 1, true, 12);   // stages chunk 31 (last)
  DO_CH(28, 3, 0, false, 8);
  DO_CH(29, 4, 0, false, 4);
  DO_CH(30, 0, 0, false, 0);
  DO_CH_LAST(1);
#undef DO_CH
#undef DO_CH_LAST
#undef WAITV
#undef BAR

  // epilogue: C/D mapping col=lane&15, row=(lane>>4)*4+r
  if constexpr (MODE == 0) {
    const int plane = bn >> 10;                 // 0: rem, 1: tanh
    const int cb    = bn & 1023;
    unsigned short* ob = plane ? ob1 : ob0;
    const float* bs    = plane ? bias1 : bias0;
    float bv[4];
    #pragma unroll
    for (int j = 0; j < 4; ++j) bv[j] = bs[cb + wn * 64 + j * 16 + frow];
    #pragma unroll
    for (int ii = 0; ii < 8; ++ii) {
      int row = bm + wm * 128 + ii * 16 + ks * 4;
      #pragma unroll
      for (int j = 0; j < 4; ++j) {
        int col = cb + wn * 64 + j * 16 + frow;
        float lin = (float)col * (1.0f / 1023.0f);
        #pragma unroll
        for (int r = 0; r < 4; ++r) {
          float z = acc[ii][j][r] + bv[j];
          float v;
          if (plane == 0) {
            v = lin / (1.0f + __expf(-z));             // rem (small, bf16-safe)
          } else {
            float e2 = __expf(2.0f * z);
            v = 1.0f - 2.0f / (e2 + 1.0f);             // tanh
          }
          ob[(size_t)(row + r) * D_ + col] = f2bf(v);
        }
      }
    }
  } else {
    float bv[4];
    #pragma unroll
    for (int j = 0; j < 4; ++j) bv[j] = bias0[bn + wn * 64 + j * 16 + frow];
    #pragma unroll
    for (int ii = 0; ii < 8; ++ii) {
      int row = bm + wm * 128 + ii * 16 + ks * 4;
      #pragma unroll
      for (int j = 0; j < 4; ++j) {
        int col = bn + wn * 64 + j * 16 + frow;
        #pragma unroll
        for (int r = 0; r < 4; ++r)
          of[(size_t)(row + r) * D_ + col] = acc[ii][j][r] + bv[j];
      }
    }
  }
}

// ---------------------------------------------------------------------------
// Chunked parallel scan over precomputed (rem, t), 4 channels/thread.
// f = 1 - rem (fp32);  h_t = f*h_{t-1} + t*rem
// ---------------------------------------------------------------------------
__global__ __launch_bounds__(256)
void scan_partial_b(const unsigned short* __restrict__ rb,
                    const unsigned short* __restrict__ tb,
                    float* __restrict__ Ag, float* __restrict__ Ug)
{
  int blk = blockIdx.x;
  int b = blk >> 7, c = blk & (CHUNKS - 1);
  int e = threadIdx.x << 2;
  size_t base = ((size_t)b * L_ + (size_t)c * TCH) * D_ + e;
  f32x4 a = {1.f,1.f,1.f,1.f}, u = {0.f,0.f,0.f,0.f};
  for (int t = 0; t < TCH; ++t) {
    ushort4v r4 = *(const ushort4v*)(rb + base + (size_t)t * D_);
    ushort4v t4 = *(const ushort4v*)(tb + base + (size_t)t * D_);
    #pragma unroll
    for (int j = 0; j < 4; ++j) {
      float rem = bf2f(r4[j]);
      float f   = 1.0f - rem;
      float inp = bf2f(t4[j]) * rem;
      u[j] = fmaf(f, u[j], inp);
      a[j] *= f;
    }
  }
  size_t o = (size_t)(b * CHUNKS + c) * D_ + e;
  *(f32x4*)(Ag + o) = a;
  *(f32x4*)(Ug + o) = u;
}

__global__ __launch_bounds__(256)
void scan_carry(const float* __restrict__ Ag, const float* __restrict__ Ug,
                const float* __restrict__ hidden, float* __restrict__ Hin)
{
  int gid = blockIdx.x * 256 + threadIdx.x;  // B_*D_/4 threads
  int b = gid >> 8;
  int e = (gid & 255) << 2;
  f32x4 h = *(const f32x4*)(hidden + (size_t)b * D_ + e);
  for (int c = 0; c < CHUNKS; ++c) {
    size_t o = (size_t)(b * CHUNKS + c) * D_ + e;
    *(f32x4*)(Hin + o) = h;
    f32x4 A = *(const f32x4*)(Ag + o);
    f32x4 U = *(const f32x4*)(Ug + o);
    h = A * h + U;
  }
}

__global__ __launch_bounds__(256)
void scan_apply_b(const unsigned short* __restrict__ rb,
                  const unsigned short* __restrict__ tb,
                  const float* __restrict__ Hin,
                  float* __restrict__ hout, unsigned short* __restrict__ hb)
{
  int blk = blockIdx.x;
  int b = blk >> 7, c = blk & (CHUNKS - 1);
  int e = threadIdx.x << 2;
  size_t base = ((size_t)b * L_ + (size_t)c * TCH) * D_ + e;
  f32x4 h = *(const f32x4*)(Hin + (size_t)(b * CHUNKS + c) * D_ + e);
  for (int t = 0; t < TCH; ++t) {
    size_t o = base + (size_t)t * D_;
    ushort4v r4 = *(const ushort4v*)(rb + o);
    ushort4v t4 = *(const ushort4v*)(tb + o);
    #pragma unroll
    for (int j = 0; j < 4; ++j) {
      float rem = bf2f(r4[j]);
      float f   = 1.0f - rem;
      float inp = bf2f(t4[j]) * rem;
      h[j] = fmaf(f, h[j], inp);
    }
    *(f32x4*)(hout + o) = h;
    ushort4v p;
    p[0] = f2bf(h[0]); p[1] = f2bf(h[1]); p[2] = f2bf(h[2]); p[3] = f2bf(h[3]);
    *(ushort4v*)(hb + o) = p;
  }
}

// ---------------------------------------------------------------------------
// Slow fallback (fp32 in) — only if ws too small (never expected).
// ---------------------------------------------------------------------------
template<int MODE>
__global__ __launch_bounds__(256, 2)
void gemm_slow(const float* __restrict__ A, const float* __restrict__ B0,
               const float* __restrict__ B1, const float* __restrict__ bias0,
               const float* __restrict__ bias1, float* __restrict__ out0,
               float* __restrict__ out1)
{
  constexpr int BK = 32;
  __shared__ unsigned short As[128 * BK];
  __shared__ unsigned short Bs0[128 * BK];
  __shared__ unsigned short Bs1[(MODE == 0) ? (128 * BK) : 8];

  const int tid = threadIdx.x, lane = tid & 63, wave = tid >> 6;
  const int wr = wave >> 1, wc = wave & 1;
  const int bm = blockIdx.x * 128, bn = blockIdx.y * 128;
  f32x4 acc0[4][4] = {};
  f32x4 acc1[(MODE == 0) ? 4 : 1][(MODE == 0) ? 4 : 1] = {};
  const int frow = lane & 15, kslot = lane >> 4;
  const int xs = kslot ^ (frow & 3);

  auto stage = [&](const float* src, unsigned short* dst) {
    #pragma unroll
    for (int p = 0; p < 4; ++p) {
      int g = p * 256 + tid;
      int row = g >> 3, kq = (g & 7) << 2;
      f32x4 v = *(const f32x4*)(src + (size_t)row * D_ + kq);
      ushort4v w;
      w[0] = f2bf(v[0]); w[1] = f2bf(v[1]); w[2] = f2bf(v[2]); w[3] = f2bf(v[3]);
      int byte = kq << 1, slot = byte >> 4, sub = byte & 15;
      int off = row * 64 + ((slot ^ (row & 3)) << 4) + sub;
      *(ushort4v*)((char*)dst + off) = w;
    }
  };

  for (int k0 = 0; k0 < D_; k0 += BK) {
    stage(A + (size_t)bm * D_ + k0, As);
    stage(B0 + (size_t)bn * D_ + k0, Bs0);
    if constexpr (MODE == 0) stage(B1 + (size_t)bn * D_ + k0, Bs1);
    __syncthreads();
    short8 af[4], bf0[4], bf1[4];
    #pragma unroll
    for (int i = 0; i < 4; ++i) {
      int ar = wr * 64 + i * 16 + frow;
      af[i] = *(const short8*)((const char*)As + ar * 64 + (xs << 4));
      int br = wc * 64 + i * 16 + frow;
      bf0[i] = *(const short8*)((const char*)Bs0 + br * 64 + (xs << 4));
      if constexpr (MODE == 0)
        bf1[i] = *(const short8*)((const char*)Bs1 + br * 64 + (xs << 4));
    }
    #pragma unroll
    for (int i = 0; i < 4; ++i)
      #pragma unroll
      for (int j = 0; j < 4; ++j) {
        acc0[i][j] = __builtin_amdgcn_mfma_f32_16x16x32_bf16(af[i], bf0[j], acc0[i][j], 0, 0, 0);
        if constexpr (MODE == 0)
          acc1[i][j] = __builtin_amdgcn_mfma_f32_16x16x32_bf16(af[i], bf1[j], acc1[i][j], 0, 0, 0);
      }
    __syncthreads();
  }
  #pragma unroll
  for (int i = 0; i < 4; ++i)
    #pragma unroll
    for (int j = 0; j < 4; ++j)
      #pragma unroll
      for (int r = 0; r < 4; ++r) {
        int row = bm + wr * 64 + i * 16 + (lane >> 4) * 4 + r;
        int col = bn + wc * 64 + j * 16 + (lane & 15);
        size_t idx = (size_t)row * D_ + col;
        if constexpr (MODE == 0) {
          float zf = acc0[i][j][r] + bias0[col];
          float linv = (float)col * (1.0f / 1023.0f);
          float rem = linv / (1.0f + __expf(-zf));
          float zi = acc1[i][j][r] + bias1[col];
          float e2 = __expf(2.0f * zi);
          float th = 1.0f - 2.0f / (e2 + 1.0f);
          out0[idx] = 1.0f - rem;
          out1[idx] = th * rem;
        } else {
          out0[idx] = acc0[i][j][r] + bias0[col];
        }
      }
}

__global__ __launch_bounds__(256)
void scan_partial_f(const float* __restrict__ p0, const float* __restrict__ p1,
                    float* __restrict__ Ag, float* __restrict__ Ug)
{
  int blk = blockIdx.x;
  int b = blk / (CHUNKS * 2);
  int c = (blk >> 1) & (CHUNKS - 1);
  int e = ((blk & 1) << 9) + threadIdx.x * 2;
  size_t base = ((size_t)b * L_ + (size_t)c * TCH) * D_ + e;
  f32x2 a = {1.0f, 1.0f}, u = {0.0f, 0.0f};
  for (int t = 0; t < TCH; ++t) {
    f32x2 f = *(const f32x2*)(p0 + base + (size_t)t * D_);
    f32x2 i = *(const f32x2*)(p1 + base + (size_t)t * D_);
    u = f * u + i;
    a = a * f;
  }
  size_t o = (size_t)(b * CHUNKS + c) * D_ + e;
  *(f32x2*)(Ag + o) = a;
  *(f32x2*)(Ug + o) = u;
}

__global__ __launch_bounds__(256)
void scan_apply_f(const float* __restrict__ p0, float* __restrict__ p1_io,
                  const float* __restrict__ Hin)
{
  int blk = blockIdx.x;
  int b = blk / (CHUNKS * 2);
  int c = (blk >> 1) & (CHUNKS - 1);
  int e = ((blk & 1) << 9) + threadIdx.x * 2;
  size_t base = ((size_t)b * L_ + (size_t)c * TCH) * D_ + e;
  f32x2 h = *(const f32x2*)(Hin + (size_t)(b * CHUNKS + c) * D_ + e);
  for (int t = 0; t < TCH; ++t) {
    size_t o = base + (size_t)t * D_;
    f32x2 f = *(const f32x2*)(p0 + o);
    f32x2 i = *(const f32x2*)(p1_io + o);
    h = f * h + i;
    *(f32x2*)(p1_io + o) = h;
  }
}

// ---------------------------------------------------------------------------
extern "C" void kernel_launch(void* const* d_in, const int* in_sizes, int n_in,
                              void* d_out, int out_size, void* d_ws, size_t ws_size,
                              hipStream_t stream)
{
  const float* x      = (const float*)d_in[0];
  const float* hidden = (const float*)d_in[1];
  const float* W_f    = (const float*)d_in[2];
  const float* b_f    = (const float*)d_in[3];
  const float* W_i    = (const float*)d_in[4];
  const float* b_i    = (const float*)d_in[5];
  const float* W_o    = (const float*)d_in[6];
  const float* b_o    = (const float*)d_in[7];

  float* y = (float*)d_out;
  float* h = y + (size_t)M_ * D_;

  const size_t xb_elems = (size_t)M_ * D_;
  const size_t w_elems  = (size_t)D_ * D_;
  const size_t agg      = (size_t)B_ * CHUNKS * D_;
  const size_t need = (xb_elems * 3 + 3 * w_elems) * 2 + agg * 3 * 4;

  if (ws_size >= need) {
    unsigned short* xb  = (unsigned short*)d_ws;       // bf16 x, later bf16 h
    unsigned short* wfb = xb + xb_elems;               // [W_f;W_i] stacked
    unsigned short* wib = wfb + w_elems;
    unsigned short* wob = wib + w_elems;
    unsigned short* rbv = wob + w_elems;               // bf16 rem
    unsigned short* tbv = rbv + xb_elems;              // bf16 tanh
    float* Ag  = (float*)(tbv + xb_elems);
    float* Ug  = Ag + agg;
    float* Hin = Ug + agg;

    cvt_bf16<<<(int)(xb_elems / 8 / 256), 256, 0, stream>>>(x, xb, (int)(xb_elems / 8));
    cvt_w3<<<3 * (int)(w_elems / 8 / 256), 256, 0, stream>>>(W_f, W_i, W_o, wfb);

    gemm256<0><<<1024, 512, 0, stream>>>(xb, wfb, b_f, b_i, rbv, tbv, nullptr);

    int pblocks = B_ * CHUNKS;               // 1024
    scan_partial_b<<<pblocks, 256, 0, stream>>>(rbv, tbv, Ag, Ug);
    scan_carry<<<(B_ * D_ / 4) / 256, 256, 0, stream>>>(Ag, Ug, hidden, Hin);
    scan_apply_b<<<pblocks, 256, 0, stream>>>(rbv, tbv, Hin, h, xb);

    gemm256<1><<<512, 512, 0, stream>>>(xb, wob, b_o, nullptr, nullptr, nullptr, y);
  } else {
    float* Ag  = (float*)d_ws;
    float* Ug  = Ag + agg;
    float* Hin = Ug + agg;
    dim3 gg(M_ / 128, D_ / 128);
    int pblocks = B_ * CHUNKS * 2;

    gemm_slow<0><<<gg, 256, 0, stream>>>(x, W_f, W_i, b_f, b_i, y, h);
    scan_partial_f<<<pblocks, 256, 0, stream>>>(y, h, Ag, Ug);
    scan_carry<<<(B_ * D_ / 4) / 256, 256, 0, stream>>>(Ag, Ug, hidden, Hin);
    scan_apply_f<<<pblocks, 256, 0, stream>>>(y, h, Hin);
    gemm_slow<1><<<gg, 256, 0, stream>>>(h, W_o, nullptr, b_o, nullptr, y, nullptr);
  }
}